// Round 1
// baseline (1949.322 us; speedup 1.0000x reference)
//
#include <hip/hip_runtime.h>
#include <math.h>

// Problem constants (fixed by the reference)
constexpr int Bc   = 2;
constexpr int Sc   = 2048;
constexpr int Dc   = 1024;   // model dim
constexpr int Hc   = 16;     // heads
constexpr int HDc  = 64;     // head dim
constexpr int WINc = 128;    // window
constexpr int HALFc = 64;    // W/2 ; band: |i-j| <= 64  -> 129 positions

// ---------------------------------------------------------------------------
// GEMM: C[M,N] = A[M,K] @ Wt[N,K]^T + bias[N]   (torch Linear)
// Tiled fp32: 64x64 tile, TK=16, 256 threads, 4x4 acc per thread.
// M=4096, N=1024, K=1024 -> all divisible, no bounds checks.
// ---------------------------------------------------------------------------
constexpr int TM = 64, TN = 64, TK = 16;

__global__ __launch_bounds__(256)
void gemm_bias(const float* __restrict__ A, const float* __restrict__ Wt,
               const float* __restrict__ bias, float* __restrict__ C,
               int M, int N, int K) {
    __shared__ float As[TM][TK + 1];
    __shared__ float Bs[TN][TK + 1];

    const int tx = threadIdx.x & 15;   // 0..15 -> col group
    const int ty = threadIdx.x >> 4;   // 0..15 -> row group
    const int row0 = blockIdx.y * TM;
    const int col0 = blockIdx.x * TN;

    float acc[4][4] = {};

    const int t  = threadIdx.x;
    const int lr = t >> 2;          // 0..63  (tile row for loads)
    const int lc = (t & 3) * 4;     // 0,4,8,12 (k offset for loads)

    for (int k0 = 0; k0 < K; k0 += TK) {
        float4 av = *(const float4*)&A [(size_t)(row0 + lr) * K + k0 + lc];
        float4 wv = *(const float4*)&Wt[(size_t)(col0 + lr) * K + k0 + lc];
        As[lr][lc + 0] = av.x; As[lr][lc + 1] = av.y;
        As[lr][lc + 2] = av.z; As[lr][lc + 3] = av.w;
        Bs[lr][lc + 0] = wv.x; Bs[lr][lc + 1] = wv.y;
        Bs[lr][lc + 2] = wv.z; Bs[lr][lc + 3] = wv.w;
        __syncthreads();

        #pragma unroll
        for (int p = 0; p < TK; ++p) {
            float a[4], b[4];
            #pragma unroll
            for (int i = 0; i < 4; ++i) a[i] = As[ty * 4 + i][p];
            #pragma unroll
            for (int j = 0; j < 4; ++j) b[j] = Bs[tx * 4 + j][p];
            #pragma unroll
            for (int i = 0; i < 4; ++i)
                #pragma unroll
                for (int j = 0; j < 4; ++j)
                    acc[i][j] += a[i] * b[j];
        }
        __syncthreads();
    }

    #pragma unroll
    for (int i = 0; i < 4; ++i) {
        const int row = row0 + ty * 4 + i;
        #pragma unroll
        for (int j = 0; j < 4; ++j) {
            const int col = col0 + tx * 4 + j;
            C[(size_t)row * N + col] = acc[i][j] + bias[col];
        }
    }
}

// ---------------------------------------------------------------------------
// Band attention: one 128-thread block per (b, h, i) query row.
//  - stage q_i (64 f32) in LDS
//  - scores for the 129 band offsets (each thread: offsets t, t+128)
//  - wave-0 softmax reduction (max, sum)
//  - write normalized probs into the (pre-zeroed) full attn row
//  - ctx[d] = sum_j p_j * v[j][d]  (threads 0..63, coalesced v reads)
// Layouts: q/k/v/ctx are [b, s, D] with e = h*HD + d (projection-natural).
// attn is [b, h, i, j].
// ---------------------------------------------------------------------------
__global__ __launch_bounds__(128)
void attn_kernel(const float* __restrict__ q, const float* __restrict__ k,
                 const float* __restrict__ v, float* __restrict__ attn,
                 float* __restrict__ ctx) {
    const int bid = blockIdx.x;            // ((b*H + h)*S + i)
    const int i = bid & (Sc - 1);
    const int h = (bid >> 11) & (Hc - 1);
    const int b = bid >> 15;

    __shared__ float qs[HDc];
    __shared__ float sc[WINc + 1];         // 129 scores
    __shared__ float s_max, s_sum;

    const int t = threadIdx.x;
    const float* qrow = q + (size_t)(b * Sc + i) * Dc + h * HDc;
    if (t < HDc) qs[t] = qrow[t];
    __syncthreads();

    const int jlo = i - HALFc;

    // scores
    for (int o = t; o <= WINc; o += 128) {
        const int j = jlo + o;
        float s = -1e30f;
        if (j >= 0 && j < Sc) {
            const float* krow = k + (size_t)(b * Sc + j) * Dc + h * HDc;
            float acc = 0.f;
            #pragma unroll
            for (int d = 0; d < HDc; ++d) acc += qs[d] * krow[d];
            s = acc * 0.125f;   // 1/sqrt(64)
        }
        sc[o] = s;
    }
    __syncthreads();

    // max over 129 (wave 0)
    if (t < 64) {
        float m = fmaxf(sc[t], sc[t + 64]);
        if (t == 0) m = fmaxf(m, sc[128]);
        #pragma unroll
        for (int off = 32; off > 0; off >>= 1)
            m = fmaxf(m, __shfl_down(m, off));
        if (t == 0) s_max = m;
    }
    __syncthreads();
    const float mx = s_max;

    for (int o = t; o <= WINc; o += 128) {
        const float s = sc[o];
        sc[o] = (s <= -1e30f) ? 0.f : expf(s - mx);
    }
    __syncthreads();

    if (t < 64) {
        float sum = sc[t] + sc[t + 64];
        if (t == 0) sum += sc[128];
        #pragma unroll
        for (int off = 32; off > 0; off >>= 1)
            sum += __shfl_down(sum, off);
        if (t == 0) s_sum = sum;
    }
    __syncthreads();
    const float inv = 1.0f / s_sum;

    float* arow = attn + ((size_t)(b * Hc + h) * Sc + i) * Sc;
    for (int o = t; o <= WINc; o += 128) {
        const float p = sc[o] * inv;
        sc[o] = p;
        const int j = jlo + o;
        if (j >= 0 && j < Sc) arow[j] = p;
    }
    __syncthreads();

    // ctx accumulation: thread t = head-dim index
    if (t < HDc) {
        const int olo = (jlo < 0) ? -jlo : 0;
        const int ohi = (jlo + WINc > Sc - 1) ? (Sc - 1 - jlo) : WINc;
        float acc = 0.f;
        for (int o = olo; o <= ohi; ++o) {
            const float* vrow = v + (size_t)(b * Sc + jlo + o) * Dc + h * HDc;
            acc += sc[o] * vrow[t];
        }
        ctx[(size_t)(b * Sc + i) * Dc + h * HDc + t] = acc;
    }
}

// ---------------------------------------------------------------------------
extern "C" void kernel_launch(void* const* d_in, const int* in_sizes, int n_in,
                              void* d_out, int out_size, void* d_ws, size_t ws_size,
                              hipStream_t stream) {
    const float* x  = (const float*)d_in[0];
    const float* Wq = (const float*)d_in[1];
    const float* bq = (const float*)d_in[2];
    const float* Wk = (const float*)d_in[3];
    const float* bk = (const float*)d_in[4];
    const float* Wv = (const float*)d_in[5];
    const float* bv = (const float*)d_in[6];
    const float* Wo = (const float*)d_in[7];
    const float* bo = (const float*)d_in[8];

    float* out  = (float*)d_out;                       // [B,S,D]
    float* attn = out + (size_t)Bc * Sc * Dc;          // [B,H,S,S]

    const size_t proj = (size_t)Bc * Sc * Dc;          // 4M floats
    float* q   = (float*)d_ws;
    float* k   = q + proj;
    float* v   = k + proj;
    float* ctx = v + proj;

    const int M = Bc * Sc;   // 4096
    dim3 gblk(256);
    dim3 ggrd(Dc / TN, M / TM);   // (16, 64)

    gemm_bias<<<ggrd, gblk, 0, stream>>>(x, Wq, bq, q, M, Dc, Dc);
    gemm_bias<<<ggrd, gblk, 0, stream>>>(x, Wk, bk, k, M, Dc, Dc);
    gemm_bias<<<ggrd, gblk, 0, stream>>>(x, Wv, bv, v, M, Dc, Dc);

    // zero the full attn output (band writes fill the rest)
    hipMemsetAsync(attn, 0, (size_t)Bc * Hc * Sc * Sc * sizeof(float), stream);

    attn_kernel<<<dim3(Bc * Hc * Sc), dim3(128), 0, stream>>>(q, k, v, attn, ctx);

    gemm_bias<<<ggrd, gblk, 0, stream>>>(ctx, Wo, bo, out, M, Dc, Dc);
}

// Round 2
// 762.654 us; speedup vs baseline: 2.5560x; 2.5560x over previous
//
#include <hip/hip_runtime.h>
#include <math.h>
#include <stdint.h>

typedef __bf16 bf16_t;
typedef __bf16 bf16x8 __attribute__((ext_vector_type(8)));
typedef __bf16 bf16x4 __attribute__((ext_vector_type(4)));
typedef float  f32x4  __attribute__((ext_vector_type(4)));

constexpr int Bc = 2, Sc = 2048, Dc = 1024, Hc = 16, HDc = 64;
constexpr size_t PROJ = (size_t)Bc * Sc * Dc;     // 4,194,304
constexpr size_t WN   = (size_t)Dc * Dc;          // 1,048,576

// async 16B global->LDS (wave-uniform LDS base + lane*16 layout required)
__device__ __forceinline__ void gload_lds16(const void* g, void* l) {
    unsigned int off = (unsigned int)(uintptr_t)l;   // low 32b of generic LDS ptr = LDS offset
    auto lp = (__attribute__((address_space(3))) unsigned int*)(uintptr_t)off;
    auto gp = (const __attribute__((address_space(1))) unsigned int*)(uintptr_t)g;
    __builtin_amdgcn_global_load_lds(gp, lp, 16, 0, 0);
}

// ---------------------------------------------------------------------------
// fp32 -> bf16 hi/lo split (elementwise, float4 vectorized)
// ---------------------------------------------------------------------------
__global__ __launch_bounds__(256)
void split_x(const float* __restrict__ src, bf16_t* __restrict__ hi,
             bf16_t* __restrict__ lo) {
    const int i = blockIdx.x * 256 + threadIdx.x;
    float4 f = ((const float4*)src)[i];
    float fv[4] = {f.x, f.y, f.z, f.w};
    bf16x4 h, l4;
    #pragma unroll
    for (int j = 0; j < 4; ++j) {
        bf16_t hh = (bf16_t)fv[j];
        h[j] = hh;
        l4[j] = (bf16_t)(fv[j] - (float)hh);
    }
    ((bf16x4*)hi)[i] = h;
    ((bf16x4*)lo)[i] = l4;
}

__global__ __launch_bounds__(256)
void split_w4(const float* __restrict__ w0, const float* __restrict__ w1,
              const float* __restrict__ w2, const float* __restrict__ w3,
              bf16_t* __restrict__ dst) {
    const int ten = blockIdx.y;
    const float* src = (ten == 0) ? w0 : (ten == 1) ? w1 : (ten == 2) ? w2 : w3;
    bf16_t* hi = dst + (size_t)ten * 2 * WN;
    bf16_t* lo = hi + WN;
    const int i = blockIdx.x * 256 + threadIdx.x;   // n4 = 262144
    float4 f = ((const float4*)src)[i];
    float fv[4] = {f.x, f.y, f.z, f.w};
    bf16x4 h, l4;
    #pragma unroll
    for (int j = 0; j < 4; ++j) {
        bf16_t hh = (bf16_t)fv[j];
        h[j] = hh;
        l4[j] = (bf16_t)(fv[j] - (float)hh);
    }
    ((bf16x4*)hi)[i] = h;
    ((bf16x4*)lo)[i] = l4;
}

// ---------------------------------------------------------------------------
// hi/lo bf16 MFMA GEMM: C[M,N] = (Ah+Al)[M,K] @ (Bh+Bl)[N,K]^T + bias
// BM=128, BN=64, BK=32, 256 threads (4 waves 2x2), K=N=1024 fixed.
// ---------------------------------------------------------------------------
template <typename OutT>
__global__ __launch_bounds__(256, 2)
void gemm_hilo(const bf16_t* __restrict__ Ah, const bf16_t* __restrict__ Al,
               const bf16_t* __restrict__ Bh, const bf16_t* __restrict__ Bl,
               const float* __restrict__ bias, OutT* __restrict__ C) {
    constexpr int K = 1024, N = 1024;
    __shared__ bf16_t sAh[128 * 32], sAl[128 * 32];
    __shared__ bf16_t sBh[64 * 32],  sBl[64 * 32];

    const int t = threadIdx.x;
    const int w = t >> 6, l = t & 63, l15 = l & 15, quad = l >> 4;
    const int row0 = blockIdx.y * 128, col0 = blockIdx.x * 64;
    const int wr = w >> 1, wc = w & 1;

    f32x4 acc[4][2];
    #pragma unroll
    for (int i = 0; i < 4; ++i)
        #pragma unroll
        for (int j = 0; j < 2; ++j) acc[i][j] = (f32x4){0.f, 0.f, 0.f, 0.f};

    const int arow = t >> 2;          // 0..63
    const int koff = (t & 3) * 8;
    const bf16_t* gah = Ah + (size_t)(row0 + arow) * K + koff;
    const bf16_t* gal = Al + (size_t)(row0 + arow) * K + koff;
    const bf16_t* gbh = Bh + (size_t)(col0 + arow) * K + koff;
    const bf16_t* gbl = Bl + (size_t)(col0 + arow) * K + koff;
    bf16_t* lA1 = sAh + w * 512;      // wave-uniform LDS bases
    bf16_t* lA2 = sAh + 2048 + w * 512;
    bf16_t* lAl1 = sAl + w * 512;
    bf16_t* lAl2 = sAl + 2048 + w * 512;
    bf16_t* lB1 = sBh + w * 512;
    bf16_t* lBl1 = sBl + w * 512;

    for (int k0 = 0; k0 < K; k0 += 32) {
        gload_lds16(gah + k0, lA1);
        gload_lds16(gah + 64 * K + k0, lA2);
        gload_lds16(gal + k0, lAl1);
        gload_lds16(gal + 64 * K + k0, lAl2);
        gload_lds16(gbh + k0, lB1);
        gload_lds16(gbl + k0, lBl1);
        __syncthreads();

        bf16x8 ah[4], al[4], bh[2], bl[2];
        #pragma unroll
        for (int mi = 0; mi < 4; ++mi) {
            const int r = (wr * 64 + mi * 16 + l15) * 32 + quad * 8;
            ah[mi] = *(const bf16x8*)&sAh[r];
            al[mi] = *(const bf16x8*)&sAl[r];
        }
        #pragma unroll
        for (int ni = 0; ni < 2; ++ni) {
            const int r = (wc * 32 + ni * 16 + l15) * 32 + quad * 8;
            bh[ni] = *(const bf16x8*)&sBh[r];
            bl[ni] = *(const bf16x8*)&sBl[r];
        }
        #pragma unroll
        for (int mi = 0; mi < 4; ++mi)
            #pragma unroll
            for (int ni = 0; ni < 2; ++ni) {
                acc[mi][ni] = __builtin_amdgcn_mfma_f32_16x16x32_bf16(ah[mi], bh[ni], acc[mi][ni], 0, 0, 0);
                acc[mi][ni] = __builtin_amdgcn_mfma_f32_16x16x32_bf16(ah[mi], bl[ni], acc[mi][ni], 0, 0, 0);
                acc[mi][ni] = __builtin_amdgcn_mfma_f32_16x16x32_bf16(al[mi], bh[ni], acc[mi][ni], 0, 0, 0);
            }
        __syncthreads();
    }

    #pragma unroll
    for (int mi = 0; mi < 4; ++mi)
        #pragma unroll
        for (int ni = 0; ni < 2; ++ni) {
            const int rbase = row0 + wr * 64 + mi * 16 + quad * 4;
            const int col = col0 + wc * 32 + ni * 16 + l15;
            const float bv = bias[col];
            #pragma unroll
            for (int r = 0; r < 4; ++r)
                C[(size_t)(rbase + r) * N + col] = (OutT)(acc[mi][ni][r] + bv);
        }
}

// ---------------------------------------------------------------------------
// Fused band attention: 1 block = 64 queries of one (b,h). 256 thr (4 waves).
// QK^T MFMA -> in-register softmax (band mask) -> P to LDS bf16 + attn global
// -> PV MFMA -> ctx global.
// ---------------------------------------------------------------------------
__global__ __launch_bounds__(256, 2)
void attn_fused(const bf16_t* __restrict__ qb, const bf16_t* __restrict__ kb,
                const bf16_t* __restrict__ vb, float* __restrict__ attn,
                float* __restrict__ ctx) {
    __shared__ bf16_t sQ[64 * 72];
    __shared__ bf16_t sK[192 * 72];     // overlaid by sP (64*200 <= 192*72) after QK
    __shared__ bf16_t sV[192 * 72];
    bf16_t* sP = sK;

    const int t = threadIdx.x, w = t >> 6, l = t & 63, l15 = l & 15, quad = l >> 4;
    const int bx = blockIdx.x;
    const int tile = bx & 31, h = (bx >> 5) & 15, b = bx >> 9;
    const int q0 = tile * 64;
    const int jbase = q0 - 64;

    // ---- P0: stage Q (64x64), K/V window (192x64) as bf16 ----
    const bf16_t* qg = qb + ((size_t)(b * Sc + q0)) * Dc + h * HDc;
    #pragma unroll
    for (int it = 0; it < 2; ++it) {
        const int idx = it * 256 + t;          // 0..511
        const int r = idx >> 3, c = (idx & 7) * 8;
        *(uint4*)&sQ[r * 72 + c] = *(const uint4*)&qg[(size_t)r * Dc + c];
    }
    #pragma unroll
    for (int it = 0; it < 6; ++it) {
        const int idx = it * 256 + t;          // 0..1535
        const int r = idx >> 3, c = (idx & 7) * 8;
        int j = jbase + r;
        j = (j < 0) ? 0 : (j > Sc - 1 ? Sc - 1 : j);
        const size_t goff = ((size_t)(b * Sc + j)) * Dc + h * HDc + c;
        *(uint4*)&sK[r * 72 + c] = *(const uint4*)&kb[goff];
        *(uint4*)&sV[r * 72 + c] = *(const uint4*)&vb[goff];
    }
    __syncthreads();

    // ---- P1: S[64x192] = Q @ K^T ; wave w owns rows [16w,16w+16) ----
    f32x4 s[12];
    #pragma unroll
    for (int nt = 0; nt < 12; ++nt) s[nt] = (f32x4){0.f, 0.f, 0.f, 0.f};
    #pragma unroll
    for (int kk = 0; kk < 64; kk += 32) {
        const bf16x8 aq = *(const bf16x8*)&sQ[(w * 16 + l15) * 72 + kk + quad * 8];
        #pragma unroll
        for (int nt = 0; nt < 12; ++nt) {
            const bf16x8 bk_ = *(const bf16x8*)&sK[(nt * 16 + l15) * 72 + kk + quad * 8];
            s[nt] = __builtin_amdgcn_mfma_f32_16x16x32_bf16(aq, bk_, s[nt], 0, 0, 0);
        }
    }

    // ---- in-register softmax; lane holds rows w*16+quad*4+r, cols nt*16+l15
    float invr[4];
    #pragma unroll
    for (int r = 0; r < 4; ++r) {
        const int row = w * 16 + quad * 4 + r;
        const int lo = (row > 64 - q0) ? row : (64 - q0);
        const int hi2 = (row + 128 < 2111 - q0) ? (row + 128) : (2111 - q0);
        float m = -1e30f;
        #pragma unroll
        for (int nt = 0; nt < 12; ++nt) {
            const int jrel = nt * 16 + l15;
            const float v = s[nt][r] * 0.125f;
            if (jrel >= lo && jrel <= hi2) m = fmaxf(m, v);
        }
        #pragma unroll
        for (int k = 1; k < 16; k <<= 1) m = fmaxf(m, __shfl_xor(m, k, 64));
        float sum = 0.f;
        #pragma unroll
        for (int nt = 0; nt < 12; ++nt) {
            const int jrel = nt * 16 + l15;
            const float v = s[nt][r] * 0.125f;
            const float e = (jrel >= lo && jrel <= hi2) ? __expf(v - m) : 0.f;
            s[nt][r] = e;
            sum += e;
        }
        #pragma unroll
        for (int k = 1; k < 16; k <<= 1) sum += __shfl_xor(sum, k, 64);
        invr[r] = 1.f / sum;
    }
    __syncthreads();   // all waves done reading sK/sQ -> safe to overlay sP

    // ---- P2: write P (full 192 cols; masked = 0) + in-band global attn ----
    float* abase = attn + ((size_t)(b * Hc + h) * Sc) * Sc;
    #pragma unroll
    for (int r = 0; r < 4; ++r) {
        const int row = w * 16 + quad * 4 + r;
        const int i = q0 + row;
        const int lo = (row > 64 - q0) ? row : (64 - q0);
        const int hi2 = (row + 128 < 2111 - q0) ? (row + 128) : (2111 - q0);
        #pragma unroll
        for (int nt = 0; nt < 12; ++nt) {
            const int jrel = nt * 16 + l15;
            const float p = s[nt][r] * invr[r];
            sP[row * 200 + jrel] = (bf16_t)p;
            if (jrel >= lo && jrel <= hi2)
                abase[(size_t)i * Sc + (jbase + jrel)] = p;
        }
    }
    __syncthreads();

    // ---- P3: ctx[64x64] = P[64x192] @ V[192x64] ----
    f32x4 o[4];
    #pragma unroll
    for (int dt = 0; dt < 4; ++dt) o[dt] = (f32x4){0.f, 0.f, 0.f, 0.f};
    #pragma unroll
    for (int ks = 0; ks < 6; ++ks) {
        const bf16x8 ap = *(const bf16x8*)&sP[(w * 16 + l15) * 200 + ks * 32 + quad * 8];
        #pragma unroll
        for (int dt = 0; dt < 4; ++dt) {
            bf16x8 bv;
            #pragma unroll
            for (int jj = 0; jj < 8; ++jj)
                bv[jj] = sV[(ks * 32 + quad * 8 + jj) * 72 + dt * 16 + l15];
            o[dt] = __builtin_amdgcn_mfma_f32_16x16x32_bf16(ap, bv, o[dt], 0, 0, 0);
        }
    }
    float* cg = ctx + ((size_t)(b * Sc + q0)) * Dc + h * HDc;
    #pragma unroll
    for (int dt = 0; dt < 4; ++dt)
        #pragma unroll
        for (int r = 0; r < 4; ++r) {
            const int row = w * 16 + quad * 4 + r;
            cg[(size_t)row * Dc + dt * 16 + l15] = o[dt][r];
        }
}

// ---------------------------------------------------------------------------
extern "C" void kernel_launch(void* const* d_in, const int* in_sizes, int n_in,
                              void* d_out, int out_size, void* d_ws, size_t ws_size,
                              hipStream_t stream) {
    const float* x  = (const float*)d_in[0];
    const float* Wq = (const float*)d_in[1];
    const float* bq = (const float*)d_in[2];
    const float* Wk = (const float*)d_in[3];
    const float* bk = (const float*)d_in[4];
    const float* Wv = (const float*)d_in[5];
    const float* bv = (const float*)d_in[6];
    const float* Wo = (const float*)d_in[7];
    const float* bo = (const float*)d_in[8];

    float* out  = (float*)d_out;
    float* attn = out + PROJ;

    char* ws = (char*)d_ws;
    bf16_t* Wsp  = (bf16_t*)ws;                       // 8 x 1M bf16 = 16 MB
    bf16_t* x_hi = (bf16_t*)(ws + 16777216);
    bf16_t* x_lo = x_hi + PROJ;
    float*  ctx  = (float*)(ws + 16777216);           // aliases x_hi/x_lo (post-QKV)
    bf16_t* q_bf = (bf16_t*)(ws + 33554432);
    bf16_t* k_bf = q_bf + PROJ;
    bf16_t* v_bf = k_bf + PROJ;
    bf16_t* ctx_hi = q_bf;                            // aliases (post-attention)
    bf16_t* ctx_lo = k_bf;

    split_x<<<dim3(PROJ / 1024), dim3(256), 0, stream>>>(x, x_hi, x_lo);
    split_w4<<<dim3(WN / 1024, 4), dim3(256), 0, stream>>>(Wq, Wk, Wv, Wo, Wsp);

    const dim3 ggrd(16, 32), gblk(256);
    gemm_hilo<bf16_t><<<ggrd, gblk, 0, stream>>>(x_hi, x_lo, Wsp + 0 * WN, Wsp + 1 * WN, bq, q_bf);
    gemm_hilo<bf16_t><<<ggrd, gblk, 0, stream>>>(x_hi, x_lo, Wsp + 2 * WN, Wsp + 3 * WN, bk, k_bf);
    gemm_hilo<bf16_t><<<ggrd, gblk, 0, stream>>>(x_hi, x_lo, Wsp + 4 * WN, Wsp + 5 * WN, bv, v_bf);

    hipMemsetAsync(attn, 0, (size_t)Bc * Hc * Sc * Sc * sizeof(float), stream);

    attn_fused<<<dim3(Bc * Hc * (Sc / 64)), dim3(256), 0, stream>>>(q_bf, k_bf, v_bf, attn, ctx);

    split_x<<<dim3(PROJ / 1024), dim3(256), 0, stream>>>(ctx, ctx_hi, ctx_lo);
    gemm_hilo<float><<<ggrd, gblk, 0, stream>>>(ctx_hi, ctx_lo, Wsp + 6 * WN, Wsp + 7 * WN, bo, out);
}

// Round 3
// 666.074 us; speedup vs baseline: 2.9266x; 1.1450x over previous
//
#include <hip/hip_runtime.h>
#include <math.h>
#include <stdint.h>

typedef _Float16 f16;
typedef f16   f16x8 __attribute__((ext_vector_type(8)));
typedef f16   f16x4 __attribute__((ext_vector_type(4)));
typedef float f32x4 __attribute__((ext_vector_type(4)));

constexpr int Bc = 2, Sc = 2048, Dc = 1024, Hc = 16, HDc = 64;
constexpr size_t PROJ = (size_t)Bc * Sc * Dc;     // 4,194,304
constexpr size_t WN   = (size_t)Dc * Dc;          // 1,048,576

// async 16B global->LDS (wave-uniform LDS base + lane*16 layout required)
__device__ __forceinline__ void gload_lds16(const void* g, void* l) {
    unsigned int off = (unsigned int)(uintptr_t)l;
    auto lp = (__attribute__((address_space(3))) unsigned int*)(uintptr_t)off;
    auto gp = (const __attribute__((address_space(1))) unsigned int*)(uintptr_t)g;
    __builtin_amdgcn_global_load_lds(gp, lp, 16, 0, 0);
}

// ---------------------------------------------------------------------------
// fp32 -> fp16 packs
// ---------------------------------------------------------------------------
__global__ __launch_bounds__(256)
void pack_x(const float* __restrict__ src, f16* __restrict__ dst) {
    const int i = blockIdx.x * 256 + threadIdx.x;
    float4 f = ((const float4*)src)[i];
    f16x4 h = {(f16)f.x, (f16)f.y, (f16)f.z, (f16)f.w};
    ((f16x4*)dst)[i] = h;
}

__global__ __launch_bounds__(256)
void pack_w(const float* __restrict__ w0, const float* __restrict__ w1,
            const float* __restrict__ w2, const float* __restrict__ w3,
            f16* __restrict__ dst) {
    const int ten = blockIdx.y;
    const float* src = (ten == 0) ? w0 : (ten == 1) ? w1 : (ten == 2) ? w2 : w3;
    f16* d = dst + (size_t)ten * WN;
    const int i = blockIdx.x * 256 + threadIdx.x;   // WN/4 = 262144 -> grid.x 1024
    float4 f = ((const float4*)src)[i];
    f16x4 h = {(f16)f.x, (f16)f.y, (f16)f.z, (f16)f.w};
    ((f16x4*)d)[i] = h;
}

// ---------------------------------------------------------------------------
// fp16 MFMA GEMM: C[M,N] = A[M,K] @ W[N,K]^T + bias ; K=1024, per-tensor N=1024
// BM=128, BN=64, BK=32, 256 threads (4 waves 2x2). Tensor = col0>>10 selects
// (bias, out) -- lets one dispatch cover fused QKV (grid.x=48) or O (grid.x=16).
// ---------------------------------------------------------------------------
template <typename OutT>
__global__ __launch_bounds__(256, 2)
void gemm_f16(const f16* __restrict__ A, const f16* __restrict__ W,
              const float* __restrict__ b0, const float* __restrict__ b1,
              const float* __restrict__ b2,
              OutT* __restrict__ o0, OutT* __restrict__ o1, OutT* __restrict__ o2) {
    constexpr int K = 1024, N = 1024;
    __shared__ f16 sA[128 * 32];
    __shared__ f16 sB[64 * 32];

    const int t = threadIdx.x;
    const int w = t >> 6, l = t & 63, l15 = l & 15, quad = l >> 4;
    const int row0 = blockIdx.y * 128, col0 = blockIdx.x * 64;
    const int wr = w >> 1, wc = w & 1;

    f32x4 acc[4][2];
    #pragma unroll
    for (int i = 0; i < 4; ++i)
        #pragma unroll
        for (int j = 0; j < 2; ++j) acc[i][j] = (f32x4){0.f, 0.f, 0.f, 0.f};

    const int arow = t >> 2;          // 0..63
    const int koff = (t & 3) * 8;     // 8 f16 = 16B
    const f16* ga = A + (size_t)(row0 + arow) * K + koff;
    const f16* gb = W + (size_t)(col0 + arow) * K + koff;
    f16* lA1 = sA + w * 512;          // wave-uniform LDS bases
    f16* lA2 = sA + 2048 + w * 512;
    f16* lB1 = sB + w * 512;

    for (int k0 = 0; k0 < K; k0 += 32) {
        gload_lds16(ga + k0, lA1);
        gload_lds16(ga + 64 * K + k0, lA2);
        gload_lds16(gb + k0, lB1);
        __syncthreads();

        f16x8 ah[4], bh[2];
        #pragma unroll
        for (int mi = 0; mi < 4; ++mi)
            ah[mi] = *(const f16x8*)&sA[(wr * 64 + mi * 16 + l15) * 32 + quad * 8];
        #pragma unroll
        for (int ni = 0; ni < 2; ++ni)
            bh[ni] = *(const f16x8*)&sB[(wc * 32 + ni * 16 + l15) * 32 + quad * 8];
        #pragma unroll
        for (int mi = 0; mi < 4; ++mi)
            #pragma unroll
            for (int ni = 0; ni < 2; ++ni)
                acc[mi][ni] = __builtin_amdgcn_mfma_f32_16x16x32_f16(ah[mi], bh[ni], acc[mi][ni], 0, 0, 0);
        __syncthreads();
    }

    const int ten = col0 >> 10;
    const float* bias = (ten == 0) ? b0 : (ten == 1) ? b1 : b2;
    OutT* out = (ten == 0) ? o0 : (ten == 1) ? o1 : o2;
    const int nc0 = col0 & (N - 1);

    #pragma unroll
    for (int mi = 0; mi < 4; ++mi)
        #pragma unroll
        for (int ni = 0; ni < 2; ++ni) {
            const int rbase = row0 + wr * 64 + mi * 16 + quad * 4;
            const int col = nc0 + wc * 32 + ni * 16 + l15;
            const float bv = bias[col];
            #pragma unroll
            for (int r = 0; r < 4; ++r)
                out[(size_t)(rbase + r) * N + col] = (OutT)(acc[mi][ni][r] + bv);
        }
}

// ---------------------------------------------------------------------------
// Fused band attention: 1 block = 64 queries of one (b,h). 256 thr (4 waves).
// Zero-fills its own 64 full attn rows (overlapped with QK^T), then band
// writes after __syncthreads (same-block ordering via vmcnt drain at barrier).
// ctx written directly as fp16 for the O-projection.
// ---------------------------------------------------------------------------
__global__ __launch_bounds__(256, 2)
void attn_fused(const f16* __restrict__ qb, const f16* __restrict__ kb,
                const f16* __restrict__ vb, float* __restrict__ attn,
                f16* __restrict__ ctx) {
    __shared__ f16 sQ[64 * 72];
    __shared__ f16 sK[192 * 72];     // overlaid by sP (64*200 <= 192*72) after QK
    __shared__ f16 sV[192 * 72];
    f16* sP = sK;

    const int t = threadIdx.x, w = t >> 6, l = t & 63, l15 = l & 15, quad = l >> 4;
    const int bx = blockIdx.x;
    const int tile = bx & 31, h = (bx >> 5) & 15, b = bx >> 9;
    const int q0 = tile * 64;
    const int jbase = q0 - 64;

    // ---- P0: stage Q (64x64), K/V window (192x64) ----
    const f16* qg = qb + ((size_t)(b * Sc + q0)) * Dc + h * HDc;
    #pragma unroll
    for (int it = 0; it < 2; ++it) {
        const int idx = it * 256 + t;          // 0..511
        const int r = idx >> 3, c = (idx & 7) * 8;
        *(uint4*)&sQ[r * 72 + c] = *(const uint4*)&qg[(size_t)r * Dc + c];
    }
    #pragma unroll
    for (int it = 0; it < 6; ++it) {
        const int idx = it * 256 + t;          // 0..1535
        const int r = idx >> 3, c = (idx & 7) * 8;
        int j = jbase + r;
        j = (j < 0) ? 0 : (j > Sc - 1 ? Sc - 1 : j);
        const size_t goff = ((size_t)(b * Sc + j)) * Dc + h * HDc + c;
        *(uint4*)&sK[r * 72 + c] = *(const uint4*)&kb[goff];
        *(uint4*)&sV[r * 72 + c] = *(const uint4*)&vb[goff];
    }
    __syncthreads();

    // ---- P1: zero-fill own 64 attn rows (overlaps QK compute) ----
    float* abase = attn + ((size_t)(b * Hc + h) * Sc) * Sc;
    {
        uint4* z = (uint4*)(abase + (size_t)q0 * Sc);   // 64*2048 f32 = 32768 uint4
        const uint4 zero = {0u, 0u, 0u, 0u};
        for (int it = 0; it < 128; ++it)
            z[it * 256 + t] = zero;
    }

    // ---- QK^T: S[64x192]; wave w owns rows [16w,16w+16) ----
    f32x4 s[12];
    #pragma unroll
    for (int nt = 0; nt < 12; ++nt) s[nt] = (f32x4){0.f, 0.f, 0.f, 0.f};
    #pragma unroll
    for (int kk = 0; kk < 64; kk += 32) {
        const f16x8 aq = *(const f16x8*)&sQ[(w * 16 + l15) * 72 + kk + quad * 8];
        #pragma unroll
        for (int nt = 0; nt < 12; ++nt) {
            const f16x8 bk_ = *(const f16x8*)&sK[(nt * 16 + l15) * 72 + kk + quad * 8];
            s[nt] = __builtin_amdgcn_mfma_f32_16x16x32_f16(aq, bk_, s[nt], 0, 0, 0);
        }
    }

    // ---- in-register softmax; lane holds rows w*16+quad*4+r, cols nt*16+l15
    float invr[4];
    #pragma unroll
    for (int r = 0; r < 4; ++r) {
        const int row = w * 16 + quad * 4 + r;
        const int lo = (row > 64 - q0) ? row : (64 - q0);
        const int hi2 = (row + 128 < 2111 - q0) ? (row + 128) : (2111 - q0);
        float m = -1e30f;
        #pragma unroll
        for (int nt = 0; nt < 12; ++nt) {
            const int jrel = nt * 16 + l15;
            const float v = s[nt][r] * 0.125f;
            if (jrel >= lo && jrel <= hi2) m = fmaxf(m, v);
        }
        #pragma unroll
        for (int k = 1; k < 16; k <<= 1) m = fmaxf(m, __shfl_xor(m, k, 64));
        float sum = 0.f;
        #pragma unroll
        for (int nt = 0; nt < 12; ++nt) {
            const int jrel = nt * 16 + l15;
            const float v = s[nt][r] * 0.125f;
            const float e = (jrel >= lo && jrel <= hi2) ? __expf(v - m) : 0.f;
            s[nt][r] = e;
            sum += e;
        }
        #pragma unroll
        for (int k = 1; k < 16; k <<= 1) sum += __shfl_xor(sum, k, 64);
        invr[r] = 1.f / sum;
    }
    __syncthreads();   // sK/sQ reads done; zero-stores drained -> band writes safe

    // ---- P2: write P (full 192 cols; masked = 0) + in-band global attn ----
    #pragma unroll
    for (int r = 0; r < 4; ++r) {
        const int row = w * 16 + quad * 4 + r;
        const int i = q0 + row;
        const int lo = (row > 64 - q0) ? row : (64 - q0);
        const int hi2 = (row + 128 < 2111 - q0) ? (row + 128) : (2111 - q0);
        #pragma unroll
        for (int nt = 0; nt < 12; ++nt) {
            const int jrel = nt * 16 + l15;
            const float p = s[nt][r] * invr[r];
            sP[row * 200 + jrel] = (f16)p;
            if (jrel >= lo && jrel <= hi2)
                abase[(size_t)i * Sc + (jbase + jrel)] = p;
        }
    }
    __syncthreads();

    // ---- P3: ctx[64x64] = P[64x192] @ V[192x64] ----
    f32x4 o[4];
    #pragma unroll
    for (int dt = 0; dt < 4; ++dt) o[dt] = (f32x4){0.f, 0.f, 0.f, 0.f};
    #pragma unroll
    for (int ks = 0; ks < 6; ++ks) {
        const f16x8 ap = *(const f16x8*)&sP[(w * 16 + l15) * 200 + ks * 32 + quad * 8];
        #pragma unroll
        for (int dt = 0; dt < 4; ++dt) {
            f16x8 bv;
            #pragma unroll
            for (int jj = 0; jj < 8; ++jj)
                bv[jj] = sV[(ks * 32 + quad * 8 + jj) * 72 + dt * 16 + l15];
            o[dt] = __builtin_amdgcn_mfma_f32_16x16x32_f16(ap, bv, o[dt], 0, 0, 0);
        }
    }
    f16* cg = ctx + ((size_t)(b * Sc + q0)) * Dc + h * HDc;
    #pragma unroll
    for (int dt = 0; dt < 4; ++dt)
        #pragma unroll
        for (int r = 0; r < 4; ++r) {
            const int row = w * 16 + quad * 4 + r;
            cg[(size_t)row * Dc + dt * 16 + l15] = (f16)o[dt][r];
        }
}

// ---------------------------------------------------------------------------
extern "C" void kernel_launch(void* const* d_in, const int* in_sizes, int n_in,
                              void* d_out, int out_size, void* d_ws, size_t ws_size,
                              hipStream_t stream) {
    const float* x  = (const float*)d_in[0];
    const float* Wq = (const float*)d_in[1];
    const float* bq = (const float*)d_in[2];
    const float* Wk = (const float*)d_in[3];
    const float* bk = (const float*)d_in[4];
    const float* Wv = (const float*)d_in[5];
    const float* bv = (const float*)d_in[6];
    const float* Wo = (const float*)d_in[7];
    const float* bo = (const float*)d_in[8];

    float* out  = (float*)d_out;
    float* attn = out + PROJ;

    char* ws = (char*)d_ws;
    f16* Wcat  = (f16*)ws;                 // [4][1024][1024] fp16 = 8 MB
    f16* x_f16 = (f16*)(ws + (size_t)8  * 1024 * 1024);
    f16* q_f16 = (f16*)(ws + (size_t)16 * 1024 * 1024);
    f16* k_f16 = (f16*)(ws + (size_t)24 * 1024 * 1024);
    f16* v_f16 = (f16*)(ws + (size_t)32 * 1024 * 1024);
    f16* c_f16 = (f16*)(ws + (size_t)40 * 1024 * 1024);

    pack_x<<<dim3(PROJ / 1024), dim3(256), 0, stream>>>(x, x_f16);
    pack_w<<<dim3(WN / 1024, 4), dim3(256), 0, stream>>>(Wq, Wk, Wv, Wo, Wcat);

    // fused QKV: N_total = 3072
    gemm_f16<f16><<<dim3(48, 32), dim3(256), 0, stream>>>(
        x_f16, Wcat, bq, bk, bv, q_f16, k_f16, v_f16);

    attn_fused<<<dim3(Bc * Hc * (Sc / 64)), dim3(256), 0, stream>>>(
        q_f16, k_f16, v_f16, attn, c_f16);

    // O projection: N = 1024 (tensor 0 only)
    gemm_f16<float><<<dim3(16, 32), dim3(256), 0, stream>>>(
        c_f16, Wcat + 3 * WN, bo, bo, bo, out, out, out);
}

// Round 4
// 661.271 us; speedup vs baseline: 2.9478x; 1.0073x over previous
//
#include <hip/hip_runtime.h>
#include <math.h>
#include <stdint.h>

typedef _Float16 f16;
typedef f16   f16x8 __attribute__((ext_vector_type(8)));
typedef f16   f16x4 __attribute__((ext_vector_type(4)));
typedef float f32x4 __attribute__((ext_vector_type(4)));

constexpr int Bc = 2, Sc = 2048, Dc = 1024, Hc = 16, HDc = 64;
constexpr size_t PROJ = (size_t)Bc * Sc * Dc;     // 4,194,304
constexpr size_t WN   = (size_t)Dc * Dc;          // 1,048,576

// async 16B global->LDS (wave-uniform LDS base + lane*16 layout required)
__device__ __forceinline__ void gload_lds16(const void* g, void* l) {
    unsigned int off = (unsigned int)(uintptr_t)l;
    auto lp = (__attribute__((address_space(3))) unsigned int*)(uintptr_t)off;
    auto gp = (const __attribute__((address_space(1))) unsigned int*)(uintptr_t)g;
    __builtin_amdgcn_global_load_lds(gp, lp, 16, 0, 0);
}

// ---------------------------------------------------------------------------
// fp32 -> fp16 pack: x (4096 blocks) + 4 weight tensors (4x1024 blocks)
// ---------------------------------------------------------------------------
__global__ __launch_bounds__(256)
void pack_all(const float* __restrict__ x,
              const float* __restrict__ w0, const float* __restrict__ w1,
              const float* __restrict__ w2, const float* __restrict__ w3,
              f16* __restrict__ xd, f16* __restrict__ wd) {
    const int bid = blockIdx.x;
    const float* src;
    f16* dst;
    int off4;
    if (bid < 4096) {
        src = x; dst = xd; off4 = bid;
    } else {
        const int wi = (bid - 4096) >> 10;
        const int r  = (bid - 4096) & 1023;
        src = (wi == 0) ? w0 : (wi == 1) ? w1 : (wi == 2) ? w2 : w3;
        dst = wd + (size_t)wi * WN;
        off4 = r;
    }
    const int i = off4 * 256 + threadIdx.x;
    float4 f = ((const float4*)src)[i];
    f16x4 h = {(f16)f.x, (f16)f.y, (f16)f.z, (f16)f.w};
    ((f16x4*)dst)[i] = h;
}

// ---------------------------------------------------------------------------
// Mega GEMM + fill dispatch.
//   blocks [0, n_gemm):  C[M,N]=A@W^T+bias, BM=BN=128, BK=32, 256 thr, 4 waves
//   blocks [n_gemm, ..): zero-fill `fill` (256 KiB/block) -- overlaps compute
// W is [n_ct*128 rows][1024]; per-1024-col tensor selects (bias, out).
// ---------------------------------------------------------------------------
template <typename OutT>
__global__ __launch_bounds__(256, 2)
void gemm_mega(const f16* __restrict__ A, const f16* __restrict__ W,
               const float* __restrict__ b0, const float* __restrict__ b1,
               const float* __restrict__ b2,
               OutT* __restrict__ o0, OutT* __restrict__ o1, OutT* __restrict__ o2,
               float* __restrict__ fill, int n_gemm, int n_ct) {
    constexpr int K = 1024, N = 1024;
    const int bid = blockIdx.x;
    const int t = threadIdx.x;

    if (bid >= n_gemm) {                      // ---- zero-fill path ----
        uint4* z = (uint4*)fill + (size_t)(bid - n_gemm) * 16384;
        const uint4 zero = {0u, 0u, 0u, 0u};
        #pragma unroll 8
        for (int it = 0; it < 64; ++it)
            z[it * 256 + t] = zero;
        return;
    }

    __shared__ f16 sA[128 * 32];
    __shared__ f16 sB[128 * 32];

    const int w = t >> 6, l = t & 63, l15 = l & 15, quad = l >> 4;
    const int col_t = bid % n_ct, row_t = bid / n_ct;
    const int row0 = row_t * 128, col0 = col_t * 128;
    const int wr = w >> 1, wc = w & 1;

    f32x4 acc[4][4];
    #pragma unroll
    for (int i = 0; i < 4; ++i)
        #pragma unroll
        for (int j = 0; j < 4; ++j) acc[i][j] = (f32x4){0.f, 0.f, 0.f, 0.f};

    const int arow = t >> 2;          // 0..63
    const int koff = (t & 3) * 8;     // 8 f16 = 16B
    const f16* ga = A + (size_t)(row0 + arow) * K + koff;
    const f16* gb = W + (size_t)(col0 + arow) * K + koff;
    f16* lA1 = sA + w * 512;          // wave-uniform LDS bases (bytes: w*1024 + lane*16)
    f16* lA2 = sA + 2048 + w * 512;
    f16* lB1 = sB + w * 512;
    f16* lB2 = sB + 2048 + w * 512;

    for (int k0 = 0; k0 < K; k0 += 32) {
        gload_lds16(ga + k0, lA1);
        gload_lds16(ga + (size_t)64 * K + k0, lA2);
        gload_lds16(gb + k0, lB1);
        gload_lds16(gb + (size_t)64 * K + k0, lB2);
        __syncthreads();

        f16x8 af[4], bf[4];
        #pragma unroll
        for (int mi = 0; mi < 4; ++mi)
            af[mi] = *(const f16x8*)&sA[(wr * 64 + mi * 16 + l15) * 32 + quad * 8];
        #pragma unroll
        for (int ni = 0; ni < 4; ++ni)
            bf[ni] = *(const f16x8*)&sB[(wc * 64 + ni * 16 + l15) * 32 + quad * 8];
        #pragma unroll
        for (int mi = 0; mi < 4; ++mi)
            #pragma unroll
            for (int ni = 0; ni < 4; ++ni)
                acc[mi][ni] = __builtin_amdgcn_mfma_f32_16x16x32_f16(af[mi], bf[ni], acc[mi][ni], 0, 0, 0);
        __syncthreads();
    }

    const int ten = col0 >> 10;                 // tile never straddles tensors
    const float* bias = (ten == 0) ? b0 : (ten == 1) ? b1 : b2;
    OutT* out = (ten == 0) ? o0 : (ten == 1) ? o1 : o2;
    const int nc0 = col0 & (N - 1);

    #pragma unroll
    for (int mi = 0; mi < 4; ++mi)
        #pragma unroll
        for (int ni = 0; ni < 4; ++ni) {
            const int rbase = row0 + wr * 64 + mi * 16 + quad * 4;
            const int col = nc0 + wc * 64 + ni * 16 + l15;
            const float bv = bias[col];
            #pragma unroll
            for (int r = 0; r < 4; ++r)
                out[(size_t)(rbase + r) * N + col] = (OutT)(acc[mi][ni][r] + bv);
        }
}

// ---------------------------------------------------------------------------
// Fused band attention: 1 block = 64 queries of one (b,h). 256 thr (4 waves).
// attn rows are pre-zeroed by gemm_mega's fill blocks; only band written here.
// ctx written directly as fp16 for the O-projection.
// ---------------------------------------------------------------------------
__global__ __launch_bounds__(256, 2)
void attn_fused(const f16* __restrict__ qb, const f16* __restrict__ kb,
                const f16* __restrict__ vb, float* __restrict__ attn,
                f16* __restrict__ ctx) {
    __shared__ f16 sQ[64 * 72];
    __shared__ f16 sK[192 * 72];     // overlaid by sP (64*200 <= 192*72) after QK
    __shared__ f16 sV[192 * 72];
    f16* sP = sK;

    const int t = threadIdx.x, w = t >> 6, l = t & 63, l15 = l & 15, quad = l >> 4;
    const int bx = blockIdx.x;
    const int tile = bx & 31, h = (bx >> 5) & 15, b = bx >> 9;
    const int q0 = tile * 64;
    const int jbase = q0 - 64;

    // ---- P0: stage Q (64x64), K/V window (192x64) ----
    const f16* qg = qb + ((size_t)(b * Sc + q0)) * Dc + h * HDc;
    #pragma unroll
    for (int it = 0; it < 2; ++it) {
        const int idx = it * 256 + t;          // 0..511
        const int r = idx >> 3, c = (idx & 7) * 8;
        *(uint4*)&sQ[r * 72 + c] = *(const uint4*)&qg[(size_t)r * Dc + c];
    }
    #pragma unroll
    for (int it = 0; it < 6; ++it) {
        const int idx = it * 256 + t;          // 0..1535
        const int r = idx >> 3, c = (idx & 7) * 8;
        int j = jbase + r;
        j = (j < 0) ? 0 : (j > Sc - 1 ? Sc - 1 : j);
        const size_t goff = ((size_t)(b * Sc + j)) * Dc + h * HDc + c;
        *(uint4*)&sK[r * 72 + c] = *(const uint4*)&kb[goff];
        *(uint4*)&sV[r * 72 + c] = *(const uint4*)&vb[goff];
    }
    __syncthreads();

    // ---- QK^T: S[64x192]; wave w owns rows [16w,16w+16) ----
    f32x4 s[12];
    #pragma unroll
    for (int nt = 0; nt < 12; ++nt) s[nt] = (f32x4){0.f, 0.f, 0.f, 0.f};
    #pragma unroll
    for (int kk = 0; kk < 64; kk += 32) {
        const f16x8 aq = *(const f16x8*)&sQ[(w * 16 + l15) * 72 + kk + quad * 8];
        #pragma unroll
        for (int nt = 0; nt < 12; ++nt) {
            const f16x8 bk_ = *(const f16x8*)&sK[(nt * 16 + l15) * 72 + kk + quad * 8];
            s[nt] = __builtin_amdgcn_mfma_f32_16x16x32_f16(aq, bk_, s[nt], 0, 0, 0);
        }
    }

    // ---- in-register softmax; lane holds rows w*16+quad*4+r, cols nt*16+l15
    float invr[4];
    #pragma unroll
    for (int r = 0; r < 4; ++r) {
        const int row = w * 16 + quad * 4 + r;
        const int lo = (row > 64 - q0) ? row : (64 - q0);
        const int hi2 = (row + 128 < 2111 - q0) ? (row + 128) : (2111 - q0);
        float m = -1e30f;
        #pragma unroll
        for (int nt = 0; nt < 12; ++nt) {
            const int jrel = nt * 16 + l15;
            const float v = s[nt][r] * 0.125f;
            if (jrel >= lo && jrel <= hi2) m = fmaxf(m, v);
        }
        #pragma unroll
        for (int k = 1; k < 16; k <<= 1) m = fmaxf(m, __shfl_xor(m, k, 64));
        float sum = 0.f;
        #pragma unroll
        for (int nt = 0; nt < 12; ++nt) {
            const int jrel = nt * 16 + l15;
            const float v = s[nt][r] * 0.125f;
            const float e = (jrel >= lo && jrel <= hi2) ? __expf(v - m) : 0.f;
            s[nt][r] = e;
            sum += e;
        }
        #pragma unroll
        for (int k = 1; k < 16; k <<= 1) sum += __shfl_xor(sum, k, 64);
        invr[r] = 1.f / sum;
    }
    __syncthreads();   // sK/sQ reads done -> safe to overlay sP

    // ---- P2: write P (full 192 cols; masked = 0) + in-band global attn ----
    float* abase = attn + ((size_t)(b * Hc + h) * Sc) * Sc;
    #pragma unroll
    for (int r = 0; r < 4; ++r) {
        const int row = w * 16 + quad * 4 + r;
        const int i = q0 + row;
        const int lo = (row > 64 - q0) ? row : (64 - q0);
        const int hi2 = (row + 128 < 2111 - q0) ? (row + 128) : (2111 - q0);
        #pragma unroll
        for (int nt = 0; nt < 12; ++nt) {
            const int jrel = nt * 16 + l15;
            const float p = s[nt][r] * invr[r];
            sP[row * 200 + jrel] = (f16)p;
            if (jrel >= lo && jrel <= hi2)
                abase[(size_t)i * Sc + (jbase + jrel)] = p;
        }
    }
    __syncthreads();

    // ---- P3: ctx[64x64] = P[64x192] @ V[192x64] ----
    f32x4 o[4];
    #pragma unroll
    for (int dt = 0; dt < 4; ++dt) o[dt] = (f32x4){0.f, 0.f, 0.f, 0.f};
    #pragma unroll
    for (int ks = 0; ks < 6; ++ks) {
        const f16x8 ap = *(const f16x8*)&sP[(w * 16 + l15) * 200 + ks * 32 + quad * 8];
        #pragma unroll
        for (int dt = 0; dt < 4; ++dt) {
            f16x8 bv;
            #pragma unroll
            for (int jj = 0; jj < 8; ++jj)
                bv[jj] = sV[(ks * 32 + quad * 8 + jj) * 72 + dt * 16 + l15];
            o[dt] = __builtin_amdgcn_mfma_f32_16x16x32_f16(ap, bv, o[dt], 0, 0, 0);
        }
    }
    f16* cg = ctx + ((size_t)(b * Sc + q0)) * Dc + h * HDc;
    #pragma unroll
    for (int dt = 0; dt < 4; ++dt)
        #pragma unroll
        for (int r = 0; r < 4; ++r) {
            const int row = w * 16 + quad * 4 + r;
            cg[(size_t)row * Dc + dt * 16 + l15] = (f16)o[dt][r];
        }
}

// ---------------------------------------------------------------------------
extern "C" void kernel_launch(void* const* d_in, const int* in_sizes, int n_in,
                              void* d_out, int out_size, void* d_ws, size_t ws_size,
                              hipStream_t stream) {
    const float* x  = (const float*)d_in[0];
    const float* Wq = (const float*)d_in[1];
    const float* bq = (const float*)d_in[2];
    const float* Wk = (const float*)d_in[3];
    const float* bk = (const float*)d_in[4];
    const float* Wv = (const float*)d_in[5];
    const float* bv = (const float*)d_in[6];
    const float* Wo = (const float*)d_in[7];
    const float* bo = (const float*)d_in[8];

    float* out  = (float*)d_out;
    float* attn = out + PROJ;

    char* ws = (char*)d_ws;
    f16* Wcat  = (f16*)ws;                 // [4][1024][1024] fp16 = 8 MB
    f16* x_f16 = (f16*)(ws + (size_t)8  * 1024 * 1024);
    f16* q_f16 = (f16*)(ws + (size_t)16 * 1024 * 1024);
    f16* k_f16 = (f16*)(ws + (size_t)24 * 1024 * 1024);
    f16* v_f16 = (f16*)(ws + (size_t)32 * 1024 * 1024);
    f16* c_f16 = (f16*)(ws + (size_t)40 * 1024 * 1024);

    pack_all<<<dim3(8192), dim3(256), 0, stream>>>(x, Wq, Wk, Wv, Wo, x_f16, Wcat);

    // fused QKV GEMM (768 blocks: 32 row-tiles x 24 col-tiles)
    //   + attn zero-fill (2048 blocks x 256 KiB = 512 MiB), overlapped
    gemm_mega<f16><<<dim3(768 + 2048), dim3(256), 0, stream>>>(
        x_f16, Wcat, bq, bk, bv, q_f16, k_f16, v_f16, attn, 768, 24);

    attn_fused<<<dim3(Bc * Hc * (Sc / 64)), dim3(256), 0, stream>>>(
        q_f16, k_f16, v_f16, attn, c_f16);

    // O projection: 256 blocks (32 x 8), no fill
    gemm_mega<float><<<dim3(256), dim3(256), 0, stream>>>(
        c_f16, Wcat + 3 * WN, bo, bo, bo, out, out, out, nullptr, 256, 8);
}

// Round 6
// 645.704 us; speedup vs baseline: 3.0189x; 1.0241x over previous
//
#include <hip/hip_runtime.h>
#include <math.h>
#include <stdint.h>

typedef _Float16 f16;
typedef f16   f16x8 __attribute__((ext_vector_type(8)));
typedef f16   f16x4 __attribute__((ext_vector_type(4)));
typedef float f32x4 __attribute__((ext_vector_type(4)));

constexpr int Bc = 2, Sc = 2048, Dc = 1024, Hc = 16, HDc = 64;
constexpr size_t PROJ = (size_t)Bc * Sc * Dc;     // 4,194,304
constexpr size_t WN   = (size_t)Dc * Dc;          // 1,048,576

// async 16B global->LDS (wave-uniform LDS base + lane*16 layout required)
__device__ __forceinline__ void gload_lds16(const void* g, void* l) {
    unsigned int off = (unsigned int)(uintptr_t)l;
    auto lp = (__attribute__((address_space(3))) unsigned int*)(uintptr_t)off;
    auto gp = (const __attribute__((address_space(1))) unsigned int*)(uintptr_t)g;
    __builtin_amdgcn_global_load_lds(gp, lp, 16, 0, 0);
}

// ---------------------------------------------------------------------------
// Band-complement zero fill: 32 rows/block; per row zero [0,a0) and [a1,2048)
// floats where a0/a1 are 32-float (128 B) aligned around the |i-j|<=64 band.
// The attn kernel writes [a0,a1) itself (zeros outside band come free from
// the masked softmax) -> no partial-cacheline sharing between writers.
// ---------------------------------------------------------------------------
__device__ __forceinline__ void fill_rows32(float* __restrict__ attn, int grow0, int t) {
    const uint4 z = {0u, 0u, 0u, 0u};
    for (int rr = 0; rr < 32; ++rr) {
        const int gr = grow0 + rr;
        const int i = gr & (Sc - 1);
        const int lo = (i > 64) ? (i - 64) : 0;
        const int a0 = lo & ~31;
        const int hi = (i < Sc - 65) ? (i + 64) : (Sc - 1);
        int a1 = (hi + 32) & ~31; if (a1 > Sc) a1 = Sc;
        uint4* rowp = (uint4*)(attn + (size_t)gr * Sc);
        const int n4L = a0 >> 2;
        const int r0  = a1 >> 2;
        const int tot = n4L + (512 - r0);
        for (int idx = t; idx < tot; idx += 256) {
            const int p = (idx < n4L) ? idx : (r0 + idx - n4L);
            rowp[p] = z;
        }
    }
}

// ---------------------------------------------------------------------------
// fp32 -> fp16 pack: x (4096 blocks) + 4 weight tensors (4x1024 blocks)
// ---------------------------------------------------------------------------
__global__ __launch_bounds__(256)
void pack_all(const float* __restrict__ x,
              const float* __restrict__ w0, const float* __restrict__ w1,
              const float* __restrict__ w2, const float* __restrict__ w3,
              f16* __restrict__ xd, f16* __restrict__ wd) {
    const int bid = blockIdx.x;
    const float* src;
    f16* dst;
    int off4;
    if (bid < 4096) {
        src = x; dst = xd; off4 = bid;
    } else {
        const int wi = (bid - 4096) >> 10;
        const int r  = (bid - 4096) & 1023;
        src = (wi == 0) ? w0 : (wi == 1) ? w1 : (wi == 2) ? w2 : w3;
        dst = wd + (size_t)wi * WN;
        off4 = r;
    }
    const int i = off4 * 256 + threadIdx.x;
    float4 f = ((const float4*)src)[i];
    f16x4 h = {(f16)f.x, (f16)f.y, (f16)f.z, (f16)f.w};
    ((f16x4*)dst)[i] = h;
}

// ---------------------------------------------------------------------------
// GEMM (+ optional interleaved fill blocks).
// GEMM: C[M,N]=A@W^T+bias, BM=BN=128, BK=32, 256 thr, 4 waves.
// WITH_FILL: grid = 2048: first 1536 interleaved in groups of 8
//            (even group -> gemm gid [0,768), odd -> fill fid [0,768)),
//            trailing 512 -> fill fid [768,1280). Fill rows = fid*32,
//            covering rows [0, 40960).
// ---------------------------------------------------------------------------
template <typename OutT, bool WITH_FILL>
__global__ __launch_bounds__(256, 2)
void gemm_mega(const f16* __restrict__ A, const f16* __restrict__ W,
               const float* __restrict__ b0, const float* __restrict__ b1,
               const float* __restrict__ b2,
               OutT* __restrict__ o0, OutT* __restrict__ o1, OutT* __restrict__ o2,
               float* __restrict__ fill, int n_ct) {
    constexpr int K = 1024, N = 1024;
    const int bid = blockIdx.x;
    const int t = threadIdx.x;

    int gid = bid;
    if (WITH_FILL) {
        int fid = -1;
        if (bid < 1536) {
            const int g8 = bid >> 3, l8 = bid & 7;
            if (g8 & 1) fid = (g8 >> 1) * 8 + l8;
            else        gid = (g8 >> 1) * 8 + l8;
        } else {
            fid = 768 + (bid - 1536);
        }
        if (fid >= 0) {
            fill_rows32(fill, fid * 32, t);
            return;
        }
    }

    __shared__ f16 sA[128 * 32];
    __shared__ f16 sB[128 * 32];

    const int w = t >> 6, l = t & 63, l15 = l & 15, quad = l >> 4;
    const int col_t = gid % n_ct, row_t = gid / n_ct;
    const int row0 = row_t * 128, col0 = col_t * 128;
    const int wr = w >> 1, wc = w & 1;

    f32x4 acc[4][4];
    #pragma unroll
    for (int i = 0; i < 4; ++i)
        #pragma unroll
        for (int j = 0; j < 4; ++j) acc[i][j] = (f32x4){0.f, 0.f, 0.f, 0.f};

    const int arow = t >> 2;          // 0..63
    const int koff = (t & 3) * 8;     // 8 f16 = 16B
    const f16* ga = A + (size_t)(row0 + arow) * K + koff;
    const f16* gb = W + (size_t)(col0 + arow) * K + koff;
    f16* lA1 = sA + w * 512;          // wave-uniform LDS bases
    f16* lA2 = sA + 2048 + w * 512;
    f16* lB1 = sB + w * 512;
    f16* lB2 = sB + 2048 + w * 512;

    for (int k0 = 0; k0 < K; k0 += 32) {
        gload_lds16(ga + k0, lA1);
        gload_lds16(ga + (size_t)64 * K + k0, lA2);
        gload_lds16(gb + k0, lB1);
        gload_lds16(gb + (size_t)64 * K + k0, lB2);
        __syncthreads();

        f16x8 af[4], bf[4];
        #pragma unroll
        for (int mi = 0; mi < 4; ++mi)
            af[mi] = *(const f16x8*)&sA[(wr * 64 + mi * 16 + l15) * 32 + quad * 8];
        #pragma unroll
        for (int ni = 0; ni < 4; ++ni)
            bf[ni] = *(const f16x8*)&sB[(wc * 64 + ni * 16 + l15) * 32 + quad * 8];
        #pragma unroll
        for (int mi = 0; mi < 4; ++mi)
            #pragma unroll
            for (int ni = 0; ni < 4; ++ni)
                acc[mi][ni] = __builtin_amdgcn_mfma_f32_16x16x32_f16(af[mi], bf[ni], acc[mi][ni], 0, 0, 0);
        __syncthreads();
    }

    const int ten = col0 >> 10;                 // tile never straddles tensors
    const float* bias = (ten == 0) ? b0 : (ten == 1) ? b1 : b2;
    OutT* out = (ten == 0) ? o0 : (ten == 1) ? o1 : o2;
    const int nc0 = col0 & (N - 1);

    #pragma unroll
    for (int mi = 0; mi < 4; ++mi)
        #pragma unroll
        for (int ni = 0; ni < 4; ++ni) {
            const int rbase = row0 + wr * 64 + mi * 16 + quad * 4;
            const int col = nc0 + wc * 64 + ni * 16 + l15;
            const float bv = bias[col];
            #pragma unroll
            for (int r = 0; r < 4; ++r)
                out[(size_t)(rbase + r) * N + col] = (OutT)(acc[mi][ni][r] + bv);
        }
}

// ---------------------------------------------------------------------------
// Fused band attention (+ interleaved fill blocks for rows [40960, 65536)).
// 1 attn block = 64 queries of one (b,h); 1024 attn blocks total. 256 thr.
// grid = 1792: first 1536 interleaved groups of 8 (even -> attn aid [0,768),
// odd -> fill fid [0,768)); trailing 256 -> attn aid [768,1024).
// attn writes the 128B-aligned window [a0,a1) per row (probs in band, zeros
// at the aligned fringes); fill blocks cover the complement of their rows.
// ---------------------------------------------------------------------------
__global__ __launch_bounds__(256, 2)
void attn_fused(const f16* __restrict__ qb, const f16* __restrict__ kb,
                const f16* __restrict__ vb, float* __restrict__ attn,
                f16* __restrict__ ctx) {
    const int bid = blockIdx.x;
    const int t = threadIdx.x;

    int aid = bid, fid = -1;
    if (bid < 1536) {
        const int g8 = bid >> 3, l8 = bid & 7;
        if (g8 & 1) fid = (g8 >> 1) * 8 + l8;      // [0,768)
        else        aid = (g8 >> 1) * 8 + l8;      // [0,768)
    } else {
        aid = 768 + (bid - 1536);                   // [768,1024)
    }
    if (fid >= 0) {
        fill_rows32(attn, 40960 + fid * 32, t);
        return;
    }

    __shared__ f16 sQ[64 * 72];
    __shared__ f16 sK[192 * 72];     // overlaid by sP (64*200 <= 192*72) after QK
    __shared__ f16 sV[192 * 72];
    f16* sP = sK;

    const int w = t >> 6, l = t & 63, l15 = l & 15, quad = l >> 4;
    const int tile = aid & 31, h = (aid >> 5) & 15, b = aid >> 9;
    const int q0 = tile * 64;
    const int jbase = q0 - 64;

    // ---- P0: stage Q (64x64), K/V window (192x64) ----
    const f16* qg = qb + ((size_t)(b * Sc + q0)) * Dc + h * HDc;
    #pragma unroll
    for (int it = 0; it < 2; ++it) {
        const int idx = it * 256 + t;          // 0..511
        const int r = idx >> 3, c = (idx & 7) * 8;
        *(uint4*)&sQ[r * 72 + c] = *(const uint4*)&qg[(size_t)r * Dc + c];
    }
    #pragma unroll
    for (int it = 0; it < 6; ++it) {
        const int idx = it * 256 + t;          // 0..1535
        const int r = idx >> 3, c = (idx & 7) * 8;
        int j = jbase + r;
        j = (j < 0) ? 0 : (j > Sc - 1 ? Sc - 1 : j);
        const size_t goff = ((size_t)(b * Sc + j)) * Dc + h * HDc + c;
        *(uint4*)&sK[r * 72 + c] = *(const uint4*)&kb[goff];
        *(uint4*)&sV[r * 72 + c] = *(const uint4*)&vb[goff];
    }
    __syncthreads();

    // ---- QK^T: S[64x192]; wave w owns rows [16w,16w+16) ----
    f32x4 s[12];
    #pragma unroll
    for (int nt = 0; nt < 12; ++nt) s[nt] = (f32x4){0.f, 0.f, 0.f, 0.f};
    #pragma unroll
    for (int kk = 0; kk < 64; kk += 32) {
        const f16x8 aq = *(const f16x8*)&sQ[(w * 16 + l15) * 72 + kk + quad * 8];
        #pragma unroll
        for (int nt = 0; nt < 12; ++nt) {
            const f16x8 bk_ = *(const f16x8*)&sK[(nt * 16 + l15) * 72 + kk + quad * 8];
            s[nt] = __builtin_amdgcn_mfma_f32_16x16x32_f16(aq, bk_, s[nt], 0, 0, 0);
        }
    }

    // ---- in-register softmax; lane holds rows w*16+quad*4+r, cols nt*16+l15
    float invr[4];
    #pragma unroll
    for (int r = 0; r < 4; ++r) {
        const int row = w * 16 + quad * 4 + r;
        const int lo = (row > 64 - q0) ? row : (64 - q0);
        const int hi2 = (row + 128 < 2111 - q0) ? (row + 128) : (2111 - q0);
        float m = -1e30f;
        #pragma unroll
        for (int nt = 0; nt < 12; ++nt) {
            const int jrel = nt * 16 + l15;
            const float v = s[nt][r] * 0.125f;
            if (jrel >= lo && jrel <= hi2) m = fmaxf(m, v);
        }
        #pragma unroll
        for (int k = 1; k < 16; k <<= 1) m = fmaxf(m, __shfl_xor(m, k, 64));
        float sum = 0.f;
        #pragma unroll
        for (int nt = 0; nt < 12; ++nt) {
            const int jrel = nt * 16 + l15;
            const float v = s[nt][r] * 0.125f;
            const float e = (jrel >= lo && jrel <= hi2) ? __expf(v - m) : 0.f;
            s[nt][r] = e;
            sum += e;
        }
        #pragma unroll
        for (int k = 1; k < 16; k <<= 1) sum += __shfl_xor(sum, k, 64);
        invr[r] = 1.f / sum;
    }
    __syncthreads();   // sK/sQ reads done -> safe to overlay sP

    // ---- P2: write P to LDS + aligned global window [a0,a1) (p=0 outside band)
    float* abase = attn + ((size_t)(b * Hc + h) * Sc) * Sc;
    #pragma unroll
    for (int r = 0; r < 4; ++r) {
        const int row = w * 16 + quad * 4 + r;
        const int i = q0 + row;
        const int lo0 = (i > 64) ? (i - 64) : 0;
        const int a0 = lo0 & ~31;
        const int hi0 = (i < Sc - 65) ? (i + 64) : (Sc - 1);
        int a1 = (hi0 + 32) & ~31; if (a1 > Sc) a1 = Sc;
        const int alo = a0 - jbase, ahi = a1 - jbase;
        #pragma unroll
        for (int nt = 0; nt < 12; ++nt) {
            const int jrel = nt * 16 + l15;
            const float p = s[nt][r] * invr[r];
            sP[row * 200 + jrel] = (f16)p;
            if (jrel >= alo && jrel < ahi)
                abase[(size_t)i * Sc + (jbase + jrel)] = p;
        }
    }
    __syncthreads();

    // ---- P3: ctx[64x64] = P[64x192] @ V[192x64] ----
    f32x4 o[4];
    #pragma unroll
    for (int dt = 0; dt < 4; ++dt) o[dt] = (f32x4){0.f, 0.f, 0.f, 0.f};
    #pragma unroll
    for (int ks = 0; ks < 6; ++ks) {
        const f16x8 ap = *(const f16x8*)&sP[(w * 16 + l15) * 200 + ks * 32 + quad * 8];
        #pragma unroll
        for (int dt = 0; dt < 4; ++dt) {
            f16x8 bv;
            #pragma unroll
            for (int jj = 0; jj < 8; ++jj)
                bv[jj] = sV[(ks * 32 + quad * 8 + jj) * 72 + dt * 16 + l15];
            o[dt] = __builtin_amdgcn_mfma_f32_16x16x32_f16(ap, bv, o[dt], 0, 0, 0);
        }
    }
    f16* cg = ctx + ((size_t)(b * Sc + q0)) * Dc + h * HDc;
    #pragma unroll
    for (int dt = 0; dt < 4; ++dt)
        #pragma unroll
        for (int r = 0; r < 4; ++r) {
            const int row = w * 16 + quad * 4 + r;
            cg[(size_t)row * Dc + dt * 16 + l15] = (f16)o[dt][r];
        }
}

// ---------------------------------------------------------------------------
extern "C" void kernel_launch(void* const* d_in, const int* in_sizes, int n_in,
                              void* d_out, int out_size, void* d_ws, size_t ws_size,
                              hipStream_t stream) {
    const float* x  = (const float*)d_in[0];
    const float* Wq = (const float*)d_in[1];
    const float* bq = (const float*)d_in[2];
    const float* Wk = (const float*)d_in[3];
    const float* bk = (const float*)d_in[4];
    const float* Wv = (const float*)d_in[5];
    const float* bv = (const float*)d_in[6];
    const float* Wo = (const float*)d_in[7];
    const float* bo = (const float*)d_in[8];

    float* out  = (float*)d_out;
    float* attn = out + PROJ;

    char* ws = (char*)d_ws;
    f16* Wcat  = (f16*)ws;                 // [4][1024][1024] fp16 = 8 MB
    f16* x_f16 = (f16*)(ws + (size_t)8  * 1024 * 1024);
    f16* q_f16 = (f16*)(ws + (size_t)16 * 1024 * 1024);
    f16* k_f16 = (f16*)(ws + (size_t)24 * 1024 * 1024);
    f16* v_f16 = (f16*)(ws + (size_t)32 * 1024 * 1024);
    f16* c_f16 = (f16*)(ws + (size_t)40 * 1024 * 1024);

    pack_all<<<dim3(8192), dim3(256), 0, stream>>>(x, Wq, Wk, Wv, Wo, x_f16, Wcat);

    // fused QKV GEMM (768 blocks) + band-complement fill rows [0,40960)
    // (1280 blocks), interleaved in groups of 8 for XCD co-residency
    gemm_mega<f16, true><<<dim3(2048), dim3(256), 0, stream>>>(
        x_f16, Wcat, bq, bk, bv, q_f16, k_f16, v_f16, attn, 24);

    // attention (1024 blocks) + fill rows [40960,65536) (768 blocks)
    attn_fused<<<dim3(1792), dim3(256), 0, stream>>>(
        q_f16, k_f16, v_f16, attn, c_f16);

    // O projection: 256 blocks (32 x 8), no fill
    gemm_mega<float, false><<<dim3(256), dim3(256), 0, stream>>>(
        c_f16, Wcat + 3 * WN, bo, bo, bo, out, out, out, nullptr, 8);
}